// Round 11
// baseline (396.367 us; speedup 1.0000x reference)
//
#include <hip/hip_runtime.h>

#define CI   128
#define TT   8192
#define CO   256
#define KW   9
#define NQ   5
#define PADL 4
#define KDIM (CI*KW)       // 1152
#define NSTEP 36           // K32 steps per q
#define NF (NQ*NSTEP)      // 180
#define BCO  128
#define BT   128
#define XROWS 136
#define XPITCH 136         // 272B rows: 17 x 16B granules (odd) -> octet-clean b128 reads

typedef __attribute__((ext_vector_type(8)))  short  short8;
typedef __attribute__((ext_vector_type(4)))  float  float4v;
typedef __attribute__((ext_vector_type(16))) float  f32x16;

static __device__ __forceinline__ short f2bf(float f) {
  union { float f; unsigned u; } c; c.f = f;
  unsigned u = c.u;
  return (short)((u + 0x7FFFu + ((u >> 16) & 1u)) >> 16);  // RNE
}

static __device__ __forceinline__ float tanh_fast(float z) {
  float e = __expf(2.f * z);
  return (e - 1.f) / (e + 1.f);
}

// ---- kernel 1: pack conv_weights (CO,CI,KW,NQ) fp32 into per-lane 32x32x16
// A-fragment stream: frag F = ((ch*NF+fi)*2+wm)*4 + mm*2 + kh, elem lane*8+j.
// A layout: co = l&31 (row), k-elem = (l>>5)*8 + j. Each wave's 4 frags/fi are
// one contiguous 4KB line -> coalesced dwordx4, L2-resident (2.95MB < 4MB/XCD).
__global__ void selfonn_wpack(const float* __restrict__ w, short* __restrict__ wpk, int n) {
  int o = blockIdx.x * 256 + threadIdx.x;
  if (o >= n) return;
  int j    = o & 7;
  int lane = (o >> 3) & 63;
  int kh   = (o >> 9) & 1;
  int mm   = (o >> 10) & 1;
  int wm   = (o >> 11) & 1;
  int ft   = o >> 12;          // 0..2*NF-1
  int ch   = ft / NF;
  int fi   = ft - ch * NF;
  int q    = fi / NSTEP;
  int step = fi - q * NSTEP;
  int k    = step >> 2;        // conv tap
  int cib  = step & 3;         // ci 32-block
  int co   = ch * 128 + wm * 64 + mm * 32 + (lane & 31);
  int ci   = cib * 32 + kh * 16 + (lane >> 5) * 8 + j;
  wpk[o] = f2bf(w[((co * CI + ci) * KW + k) * NQ + q]);
}

// ---- kernel 2: fused implicit-GEMM conv + nonlinearities + weighted sum ----
// Barrier-free main loop; 32x32x16 MFMA (8/fi/wave); weights stream
// global->VGPR (ring-3, depth-2); x tile static in LDS; 2 blocks/CU.
__global__ __launch_bounds__(256, 2) void selfonn_main(
    const float* __restrict__ x, const short* __restrict__ wpk,
    const float* __restrict__ probs, float* __restrict__ out) {

  __shared__ __align__(16) short xs[XROWS][XPITCH];   // 36992 B
  __shared__ float opw[BCO][NQ];                      // 2560 B

  const int tid  = threadIdx.x;
  const int lane = tid & 63;
  const int wid  = tid >> 6;   // 0..3
  const int wm   = wid >> 1;   // co half
  const int wt   = wid & 1;    // t half
  const int la31 = lane & 31;
  const int lh   = lane >> 5;  // 0..1
  const int b    = blockIdx.z;
  const int ch   = blockIdx.y;          // co 128-half of 256
  const int co0  = ch * BCO;
  const int t0   = blockIdx.x * BT;

  // operator softmax -> LDS
  if (tid < BCO) {
    float p[NQ];
    float mx = -1e30f;
    #pragma unroll
    for (int j = 0; j < NQ; ++j) { p[j] = probs[(co0 + tid) * NQ + j]; mx = fmaxf(mx, p[j]); }
    float s = 0.f;
    #pragma unroll
    for (int j = 0; j < NQ; ++j) { p[j] = __expf(p[j] - mx); s += p[j]; }
    float inv = 1.0f / s;
    #pragma unroll
    for (int j = 0; j < NQ; ++j) opw[tid][j] = p[j] * inv;
  }

  // stage x tile once (t-transposed, bf16): xs[tl][ci] = x[b][ci][t0-4+tl]
  const float* xb = x + (size_t)b * CI * TT;
  #pragma unroll
  for (int it = 0; it < 17; ++it) {
    int cell = tid + it * 256;          // 0..4351
    int ci = cell & (CI - 1);
    int tc = cell >> 7;                 // 0..33
    int tg = t0 - PADL + tc * 4;
    float4v v = {0.f, 0.f, 0.f, 0.f};
    if (tg >= 0 && tg <= TT - 4)
      v = *(const float4v*)(xb + (size_t)ci * TT + tg);
    int tl = tc * 4;
    xs[tl + 0][ci] = f2bf(v[0]);
    xs[tl + 1][ci] = f2bf(v[1]);
    xs[tl + 2][ci] = f2bf(v[2]);
    xs[tl + 3][ci] = f2bf(v[3]);
  }

  // B-frag bases (shorts): B col t = la31 (+row offsets), k-elem = lh*8+j.
  // addr = bro[nn] + k*XPITCH + (sq&3)*32 + kh*16
  int bro[2];
  #pragma unroll
  for (int n = 0; n < 2; ++n)
    bro[n] = (wt * 64 + n * 32 + la31) * XPITCH + (lh << 3);

  // wave's packed-weight stream pointer (shorts): fi=0 frag base
  const short* wp = wpk + ((size_t)(ch * NF) * 2 + wm) * 2048 + lane * 8;

  f32x16 oacc[2][2];
  f32x16 acc[2][2];
  #pragma unroll
  for (int m = 0; m < 2; ++m)
    #pragma unroll
    for (int n = 0; n < 2; ++n) {
      #pragma unroll
      for (int r = 0; r < 16; ++r) { oacc[m][n][r] = 0.f; acc[m][n][r] = 0.f; }
    }

  __syncthreads();   // xs/opw ready; no further barriers

  short8 W0[4], W1[4], W2[4], BA[4], BB[4];
  // prologue: W(0)->W0, W(1)->W1, B(0)->BA
  #pragma unroll
  for (int i = 0; i < 4; ++i) W0[i] = *(const short8*)(wp + i * 512);
  #pragma unroll
  for (int i = 0; i < 4; ++i) W1[i] = *(const short8*)(wp + 4096 + i * 512);
  wp += 8192;    // now points at fi=2's frag base
  #pragma unroll
  for (int n = 0; n < 2; ++n)
    #pragma unroll
    for (int kh = 0; kh < 2; ++kh)
      BA[n * 2 + kh] = *(const short8*)(&xs[0][0] + bro[n] + kh * 16);

  int sq = 0, q = 0;

  #define STEP(CW, CB, NW, NB, PFW, PFB, EPI)                          \
    {                                                                  \
      if (PFW) {                                                       \
        /* prefetch weight frags(fi+2): linear stream, 8KB per fi */   \
        _Pragma("unroll") for (int i = 0; i < 4; ++i)                  \
          NW[i] = *(const short8*)(wp + i * 512);                      \
        wp += 4096;                                                    \
      }                                                                \
      if (PFB) {                                                       \
        /* prefetch B frags(fi+1) from static xs */                    \
        int sqn = (sq == NSTEP - 1) ? 0 : sq + 1;                      \
        const short* xp = &xs[0][0] + (sqn >> 2) * XPITCH + ((sqn & 3) << 5); \
        _Pragma("unroll") for (int n = 0; n < 2; ++n)                  \
          _Pragma("unroll") for (int kh = 0; kh < 2; ++kh)             \
            NB[n * 2 + kh] = *(const short8*)(xp + bro[n] + kh * 16);  \
      }                                                                \
      __builtin_amdgcn_s_setprio(1);                                   \
      _Pragma("unroll") for (int m = 0; m < 2; ++m)                    \
        _Pragma("unroll") for (int n = 0; n < 2; ++n)                  \
          _Pragma("unroll") for (int kh = 0; kh < 2; ++kh)             \
            acc[m][n] = __builtin_amdgcn_mfma_f32_32x32x16_bf16(       \
                CW[m * 2 + kh], CB[n * 2 + kh], acc[m][n], 0, 0, 0);   \
      __builtin_amdgcn_s_setprio(0);                                   \
      if (EPI && sq == NSTEP - 1) {                                    \
        _Pragma("unroll") for (int m = 0; m < 2; ++m) {                \
          _Pragma("unroll") for (int r = 0; r < 16; ++r) {             \
            int co_l = wm * 64 + m * 32 + (r & 3) + ((r >> 2) << 3) + (lh << 2); \
            float wqv = opw[co_l][q];                                  \
            _Pragma("unroll") for (int n = 0; n < 2; ++n) {            \
              float z = acc[m][n][r];                                  \
              float f;                                                 \
              if (q == 0)      f = z;                                  \
              else if (q == 1) f = __sinf(z);                          \
              else if (q == 2) f = __cosf(z);                          \
              else if (q == 3) f = tanh_fast(z);                       \
              else             f = __expf(fminf(fmaxf(z, -8.f), 8.f)); \
              oacc[m][n][r] += wqv * f;                                \
              acc[m][n][r] = 0.f;                                      \
            }                                                          \
          }                                                            \
        }                                                              \
        ++q; sq = 0;                                                   \
      } else {                                                         \
        ++sq;                                                          \
      }                                                                \
    }

  // 6-step unroll: W sets period-3, B sets period-2; epilogues (sq==35)
  // always land at position 5 (35,71,107,143,179 all == 5 mod 6).
  for (int u = 0; u < 29; ++u) {        // fi = 0..173
    STEP(W0, BA, W2, BB, 1, 1, 0)
    STEP(W1, BB, W0, BA, 1, 1, 0)
    STEP(W2, BA, W1, BB, 1, 1, 0)
    STEP(W0, BB, W2, BA, 1, 1, 0)
    STEP(W1, BA, W0, BB, 1, 1, 0)
    STEP(W2, BB, W1, BA, 1, 1, 1)
  }
  // tail fi = 174..179
  STEP(W0, BA, W2, BB, 1, 1, 0)   // 174: prefetch W(176), B(175)
  STEP(W1, BB, W0, BA, 1, 1, 0)   // 175: prefetch W(177), B(176)
  STEP(W2, BA, W1, BB, 1, 1, 0)   // 176: prefetch W(178), B(177)
  STEP(W0, BB, W2, BA, 1, 1, 0)   // 177: prefetch W(179), B(178)
  STEP(W1, BA, W0, BB, 0, 1, 0)   // 178: prefetch B(179) only
  STEP(W2, BB, W1, BA, 0, 0, 1)   // 179: epilogue q=4
  #undef STEP

  // store (B, CO, T) fp32: C/D layout col=la31, row=(r&3)+8*(r>>2)+4*lh
  float* ob = out + (size_t)(b * CO + co0) * TT;
  #pragma unroll
  for (int m = 0; m < 2; ++m) {
    #pragma unroll
    for (int r = 0; r < 16; ++r) {
      int co_l = wm * 64 + m * 32 + (r & 3) + ((r >> 2) << 3) + (lh << 2);
      #pragma unroll
      for (int n = 0; n < 2; ++n) {
        int tcol = t0 + wt * 64 + n * 32 + la31;
        ob[(size_t)co_l * TT + tcol] = oacc[m][n][r];
      }
    }
  }
}

extern "C" void kernel_launch(void* const* d_in, const int* in_sizes, int n_in,
                              void* d_out, int out_size, void* d_ws, size_t ws_size,
                              hipStream_t stream) {
  const float* x     = (const float*)d_in[0];
  const float* w     = (const float*)d_in[1];
  const float* probs = (const float*)d_in[2];
  float* out = (float*)d_out;
  short* wpk = (short*)d_ws;   // NQ*CO*KDIM*2 = 2.95 MB

  int nw = NQ * CO * KDIM;     // 1,474,560
  selfonn_wpack<<<dim3((nw + 255) / 256), 256, 0, stream>>>(w, wpk, nw);

  dim3 grid(TT / BT, CO / BCO, 16);
  selfonn_main<<<grid, 256, 0, stream>>>(x, wpk, probs, out);
}